// Round 9
// baseline (617.539 us; speedup 1.0000x reference)
//
#include <hip/hip_runtime.h>

#define T_STEPS 1024
#define BATCH 2048
#define BTILE 4   // v17: 4 batch rows/block -> 512 blocks -> 2 blocks/CU, de-phased
#define HS 36     // LDS row stride in u32 words; 36 % 32 == 4 -> conflict-free b128 reads

typedef short short8 __attribute__((ext_vector_type(8)));
typedef float f32x4 __attribute__((ext_vector_type(4)));
typedef float f32x2 __attribute__((ext_vector_type(2)));

__device__ __forceinline__ float fast_rcp(float x) {
#if __has_builtin(__builtin_amdgcn_rcpf)
    return __builtin_amdgcn_rcpf(x);
#else
    return 1.0f / x;
#endif
}

__device__ __forceinline__ float fast_exp2(float x) {
#if __has_builtin(__builtin_amdgcn_exp2f)
    return __builtin_amdgcn_exp2f(x);
#else
    return exp2f(x);
#endif
}

__device__ __forceinline__ float sigf(float x) {
    return fast_rcp(1.0f + fast_exp2(-1.44269504f * x));
}

// packed 2-lane sigmoid
__device__ __forceinline__ f32x2 sigf2(f32x2 v) {
    f32x2 t = v * (-1.44269504f);
    f32x2 e = {fast_exp2(t[0]), fast_exp2(t[1])};
    e = e + 1.0f;
    return f32x2{fast_rcp(e[0]), fast_rcp(e[1])};
}

__device__ __forceinline__ float tanh_fast(float x) {
    float e = fast_exp2(2.88539008f * x);
    return 1.0f - 2.0f * fast_rcp(e + 1.0f);
}

// float -> bf16 bits (RNE) — setup only
__device__ __forceinline__ unsigned f2bf(float x) {
    unsigned u = __float_as_uint(x);
    unsigned r = u + 0x7FFFu + ((u >> 16) & 1u);
    return r >> 16;
}
__device__ __forceinline__ float bf2f(unsigned b) {
    return __uint_as_float(b << 16);
}

__device__ __forceinline__ unsigned cvt_pk_bf16(float a, float b) {
    unsigned r;
    asm("v_cvt_pk_bf16_f32 %0, %1, %2" : "=v"(r) : "v"(a), "v"(b));
    return r;
}

// DPP conventions (HW-validated): 0x110+N: lane l <- lane l-N (row-16);
// 0x100+N: lane l <- lane l+N. bank_mask: unselected banks keep OLD dst value.
__device__ __forceinline__ float sel4A(f32x4 a) {
    int v = __float_as_int(a[0]);                                        // bank 0 (r=0)
    v = __builtin_amdgcn_update_dpp(v, __float_as_int(a[1]), 0x114, 0xf, 0x2, false);
    v = __builtin_amdgcn_update_dpp(v, __float_as_int(a[2]), 0x118, 0xf, 0x4, false);
    v = __builtin_amdgcn_update_dpp(v, __float_as_int(a[3]), 0x11C, 0xf, 0x8, false);
    return __int_as_float(v);
}
__device__ __forceinline__ float dpp_shl4f(float v) {
    return __int_as_float(__builtin_amdgcn_update_dpp(0, __float_as_int(v), 0x104, 0xf, 0xf, true));
}

// Per-step barrier without the vmcnt(0) drain __syncthreads() emits.
// All in-loop cross-wave traffic is LDS (lgkmcnt(0)+s_barrier orders it);
// global ops are write-only stores / same-thread prefetch.
__device__ __forceinline__ void step_barrier() {
    asm volatile("s_waitcnt lgkmcnt(0)\n\ts_barrier" ::: "memory");
}

// ===================== v17: v16 structure @ 2 de-phased blocks/CU ===========
// v16 @1 block/CU measured 1034 cyc/step vs ~550 static chain -> ~500 cyc of
// exposed latency per step that nothing hides (VALUBusy 40%). v17 halves
// BTILE to 4 (512 blocks, 2/CU) with NO duplicated work: activation drops to
// 1 cell/thread (v8's proven sel4A + dpp_shl4f pack), MFMA count unchanged,
// so per-CU issue is ~constant while two independent block chains interleave
// per SIMD. Co-resident pair (b, b+256) de-phased ~half a step. Wave-4 L2
// (v16's dedicated-wave GEMV + serial recurrence) unchanged, lanes<4.
__global__ __launch_bounds__(320, 2)
void lstm_v17_kernel(const float* __restrict__ input,
                     const float* __restrict__ W_ih0,
                     const float* __restrict__ W_hh0,
                     const float* __restrict__ b_ih0,
                     const float* __restrict__ b_hh0,
                     const float* __restrict__ W_ih1,
                     const float* __restrict__ W_hh1,
                     const float* __restrict__ b_ih1,
                     const float* __restrict__ b_hh1,
                     float* __restrict__ out)
{
    const int tid = threadIdx.x;
    const int w8  = tid >> 6;        // wave 0..3 = L1 compute, wave 4 = L2
    const int l   = tid & 63;
    const int q16 = l >> 4;
    const int n16 = l & 15;
    const int nb  = l & 3;           // batch within block (4 real)
    const int r   = (l >> 2) & 3;
    const int u   = 16 * w8 + 4 * q16 + r;   // this thread's unit (w8<4)
    const int bbase = blockIdx.x * BTILE;

    __shared__ __align__(16) unsigned Hbuf[2][3][16][HS];   // h, c_hi, c_lo planes
    __shared__ float Xb[2][BTILE][65];                      // 2.1 KB

    for (int i = tid; i < 2 * 3 * 16 * HS; i += 320)
        reinterpret_cast<unsigned*>(Hbuf)[i] = 0u;

    // ---- compute-wave constants ----
    short8 a1[4][2];
    f32x2 w01, w23, b01, b23;
    if (w8 < 4) {
        #pragma unroll
        for (int g = 0; g < 4; ++g) {
            #pragma unroll
            for (int kt = 0; kt < 2; ++kt) {
                const float* p = W_hh0 + (size_t)(16 * (w8 + 4 * g) + n16) * 64 + kt * 32 + q16 * 8;
                short8 a;
                #pragma unroll
                for (int j = 0; j < 8; ++j) a[j] = (short)f2bf(p[j]);
                a1[g][kt] = a;
            }
        }
        float wgv[4], bgv[4];
        #pragma unroll
        for (int g = 0; g < 4; ++g) {
            int row = g * 64 + u;
            wgv[g] = W_ih0[row];
            bgv[g] = b_ih0[row] + b_hh0[row];
        }
        w01 = f32x2{wgv[0], wgv[1]}; w23 = f32x2{wgv[2], wgv[3]};
        b01 = f32x2{bgv[0], bgv[1]}; b23 = f32x2{bgv[2], bgv[3]};
    }

    // ---- wave-4 constants: L2 A-fragments (hi/lo split) + recurrence ----
    short8 a2h[2], a2l[2];
    float wh1[4], bb1[4];
    if (w8 == 4) {
        #pragma unroll
        for (int kt = 0; kt < 2; ++kt) {
            short8 ah = {0,0,0,0,0,0,0,0}, al = {0,0,0,0,0,0,0,0};
            if (n16 < 4) {
                const float* p = W_ih1 + (size_t)n16 * 64 + kt * 32 + q16 * 8;
                #pragma unroll
                for (int j = 0; j < 8; ++j) {
                    unsigned hb = f2bf(p[j]);
                    ah[j] = (short)hb;
                    al[j] = (short)f2bf(p[j] - bf2f(hb));
                }
            }
            a2h[kt] = ah; a2l[kt] = al;
        }
        #pragma unroll
        for (int g = 0; g < 4; ++g) { wh1[g] = W_hh1[g]; bb1[g] = b_ih1[g] + b_hh1[g]; }
    }

    // ---- input staging: waves 0..3 each stage their batch row ----
    const float* inrow = input + (size_t)(bbase + (w8 & 3)) * T_STEPS;
    if (w8 < 4) Xb[0][w8][l] = inrow[l];
    float xnext = 0.0f;
    float c0 = 0.0f;
    float h1 = 0.0f, c1 = 0.0f;      // wave-4 L2 state (lanes 0..3)

    __syncthreads();

    // ---- de-phase: co-resident pair (b, b+256) offset by ~half a step ----
    if (blockIdx.x & 256) {
        __builtin_amdgcn_s_sleep(8);
    }

    int par = 0;
    #pragma unroll 2
    for (int t = 0; t < T_STEPS; ++t) {
        if (w8 < 4) {
            if ((t & 63) == 0 && t + 64 < T_STEPS) xnext = inrow[t + 64 + l];
            const int cp = (t >> 6) & 1;

            // ---- B-fragments: h(t-1); rows(batches) 4..15 are zero ----
            const unsigned* Hrow = &Hbuf[par][0][n16][0];
            short8 hb0 = *reinterpret_cast<const short8*>(Hrow + 4 * q16);
            short8 hb1 = *reinterpret_cast<const short8*>(Hrow + 16 + 4 * q16);

            // ---- L1 MFMA ----
            f32x4 accv[4];
            #pragma unroll
            for (int g = 0; g < 4; ++g) {
                f32x4 z = {0.0f, 0.0f, 0.0f, 0.0f};
                z = __builtin_amdgcn_mfma_f32_16x16x32_bf16(a1[g][0], hb0, z, 0, 0, 0);
                z = __builtin_amdgcn_mfma_f32_16x16x32_bf16(a1[g][1], hb1, z, 0, 0, 0);
                accv[g] = z;
            }

            // ---- in-register gate redistribution (bank-masked DPP, 12 inst) ----
            float g4[4];
            #pragma unroll
            for (int g = 0; g < 4; ++g) g4[g] = sel4A(accv[g]);

            // ---- layer-1 activation for cell (nb, u), packed math ----
            float x = Xb[cp][nb][t & 63];
            f32x2 xx = {x, x};
            f32x2 gif = f32x2{g4[0], g4[1]} + (xx * w01 + b01);   // (i, f)
            f32x2 ggo = f32x2{g4[2], g4[3]} + (xx * w23 + b23);   // (g, o)

            f32x2 sif = sigf2(gif);                  // sig(i), sig(f)
            float tg  = tanh_fast(ggo[0]);
            float c0n = sif[1] * c0 + sif[0] * tg;
            c0 = c0n;
            float h0n = sigf(ggo[1]) * tanh_fast(c0n);

            // ---- pack h / c0hi / c0lo pairs via cvt_pk + partner DPP ----
            float ph = dpp_shl4f(h0n);               // partner unit u+1 (lane l+4)
            float pc = dpp_shl4f(c0n);
            unsigned hword  = cvt_pk_bf16(h0n, ph);  // lo=own, hi=partner
            unsigned chword = cvt_pk_bf16(c0n, pc);
            float hi_own = bf2f(chword & 0xFFFFu);   // own bf16(c0n) as f32
            float lo_own = c0n - hi_own;
            float plo = dpp_shl4f(lo_own);
            unsigned clword = cvt_pk_bf16(lo_own, plo);
            if (!(l & 4)) {                          // r even: owns pair (u, u+1)
                int widx = 8 * w8 + 2 * q16 + (r >> 1);
                Hbuf[par ^ 1][0][nb][widx] = hword;
                Hbuf[par ^ 1][1][nb][widx] = chword;
                Hbuf[par ^ 1][2][nb][widx] = clword;
            }
            if ((t & 63) == 63 && t + 1 < T_STEPS) Xb[cp ^ 1][w8][l] = xnext;
        } else {
            // ---- wave 4: L2 GEMV (6 MFMA, hi/lo) + recurrence for step t-1 ----
            if (t > 0) {
                const unsigned* Ch = &Hbuf[par][1][n16][0];
                const unsigned* Cl = &Hbuf[par][2][n16][0];
                short8 ch0 = *reinterpret_cast<const short8*>(Ch + 4 * q16);
                short8 ch1 = *reinterpret_cast<const short8*>(Ch + 16 + 4 * q16);
                short8 cl0 = *reinterpret_cast<const short8*>(Cl + 4 * q16);
                short8 cl1 = *reinterpret_cast<const short8*>(Cl + 16 + 4 * q16);
                f32x4 zA = {0.0f, 0.0f, 0.0f, 0.0f};
                f32x4 zB = {0.0f, 0.0f, 0.0f, 0.0f};
                zA = __builtin_amdgcn_mfma_f32_16x16x32_bf16(a2h[0], ch0, zA, 0, 0, 0);
                zB = __builtin_amdgcn_mfma_f32_16x16x32_bf16(a2l[1], ch1, zB, 0, 0, 0);
                zA = __builtin_amdgcn_mfma_f32_16x16x32_bf16(a2h[1], ch1, zA, 0, 0, 0);
                zB = __builtin_amdgcn_mfma_f32_16x16x32_bf16(a2h[0], cl0, zB, 0, 0, 0);
                zA = __builtin_amdgcn_mfma_f32_16x16x32_bf16(a2l[0], ch0, zA, 0, 0, 0);
                zB = __builtin_amdgcn_mfma_f32_16x16x32_bf16(a2h[1], cl1, zB, 0, 0, 0);
                f32x4 z = zA + zB;
                if (l < BTILE) {
                    float gi = z[0] + bb1[0] + h1 * wh1[0];
                    float gf = z[1] + bb1[1] + h1 * wh1[1];
                    float gg = z[2] + bb1[2] + h1 * wh1[2];
                    float go = z[3] + bb1[3] + h1 * wh1[3];
                    float c1n = sigf(gf) * c1 + sigf(gi) * tanh_fast(gg);
                    c1 = c1n;
                    h1 = sigf(go) * tanh_fast(c1n);
                    out[(size_t)(bbase + l) * T_STEPS + (t - 1)] = c1n;
                }
            }
        }

        step_barrier();
        par ^= 1;
    }

    // ---- epilogue: wave 4 processes step 1023 ----
    if (w8 == 4) {
        const unsigned* Ch = &Hbuf[par][1][n16][0];
        const unsigned* Cl = &Hbuf[par][2][n16][0];
        short8 ch0 = *reinterpret_cast<const short8*>(Ch + 4 * q16);
        short8 ch1 = *reinterpret_cast<const short8*>(Ch + 16 + 4 * q16);
        short8 cl0 = *reinterpret_cast<const short8*>(Cl + 4 * q16);
        short8 cl1 = *reinterpret_cast<const short8*>(Cl + 16 + 4 * q16);
        f32x4 zA = {0.0f, 0.0f, 0.0f, 0.0f};
        f32x4 zB = {0.0f, 0.0f, 0.0f, 0.0f};
        zA = __builtin_amdgcn_mfma_f32_16x16x32_bf16(a2h[0], ch0, zA, 0, 0, 0);
        zB = __builtin_amdgcn_mfma_f32_16x16x32_bf16(a2l[1], ch1, zB, 0, 0, 0);
        zA = __builtin_amdgcn_mfma_f32_16x16x32_bf16(a2h[1], ch1, zA, 0, 0, 0);
        zB = __builtin_amdgcn_mfma_f32_16x16x32_bf16(a2h[0], cl0, zB, 0, 0, 0);
        zA = __builtin_amdgcn_mfma_f32_16x16x32_bf16(a2l[0], ch0, zA, 0, 0, 0);
        zB = __builtin_amdgcn_mfma_f32_16x16x32_bf16(a2h[1], cl1, zB, 0, 0, 0);
        f32x4 z = zA + zB;
        if (l < BTILE) {
            float gi = z[0] + bb1[0] + h1 * wh1[0];
            float gf = z[1] + bb1[1] + h1 * wh1[1];
            float gg = z[2] + bb1[2] + h1 * wh1[2];
            float c1n = sigf(gf) * c1 + sigf(gi) * tanh_fast(gg);
            out[(size_t)(bbase + l) * T_STEPS + (T_STEPS - 1)] = c1n;
        }
    }
}

extern "C" void kernel_launch(void* const* d_in, const int* in_sizes, int n_in,
                              void* d_out, int out_size, void* d_ws, size_t ws_size,
                              hipStream_t stream) {
    const float* input = (const float*)d_in[0];
    const float* W_ih0 = (const float*)d_in[1];
    const float* W_hh0 = (const float*)d_in[2];
    const float* b_ih0 = (const float*)d_in[3];
    const float* b_hh0 = (const float*)d_in[4];
    const float* W_ih1 = (const float*)d_in[5];
    const float* W_hh1 = (const float*)d_in[6];
    const float* b_ih1 = (const float*)d_in[7];
    const float* b_hh1 = (const float*)d_in[8];
    float* out = (float*)d_out;

    lstm_v17_kernel<<<dim3(BATCH / BTILE), dim3(320), 0, stream>>>(
        input, W_ih0, W_hh0, b_ih0, b_hh0, W_ih1, W_hh1, b_ih1, b_hh1, out);
}

// Round 10
// 509.559 us; speedup vs baseline: 1.2119x; 1.2119x over previous
//
#include <hip/hip_runtime.h>

#define T_STEPS 1024
#define BATCH 2048
#define BTILE 8   // 8 batch rows/block -> 256 blocks -> 1 block/CU
#define HS 36     // LDS row stride in u32 words; 36 % 32 == 4 -> conflict-free b128 reads

typedef short short8 __attribute__((ext_vector_type(8)));
typedef float f32x4 __attribute__((ext_vector_type(4)));
typedef float f32x2 __attribute__((ext_vector_type(2)));

__device__ __forceinline__ float fast_rcp(float x) {
#if __has_builtin(__builtin_amdgcn_rcpf)
    return __builtin_amdgcn_rcpf(x);
#else
    return 1.0f / x;
#endif
}

__device__ __forceinline__ float fast_exp2(float x) {
#if __has_builtin(__builtin_amdgcn_exp2f)
    return __builtin_amdgcn_exp2f(x);
#else
    return exp2f(x);
#endif
}

__device__ __forceinline__ float sigf(float x) {
    return fast_rcp(1.0f + fast_exp2(-1.44269504f * x));
}

__device__ __forceinline__ f32x2 sigf2(f32x2 v) {
    f32x2 t = v * (-1.44269504f);
    f32x2 e = {fast_exp2(t[0]), fast_exp2(t[1])};
    e = e + 1.0f;
    return f32x2{fast_rcp(e[0]), fast_rcp(e[1])};
}

__device__ __forceinline__ float tanh_fast(float x) {
    float e = fast_exp2(2.88539008f * x);
    return 1.0f - 2.0f * fast_rcp(e + 1.0f);
}

__device__ __forceinline__ f32x2 tanh2(f32x2 v) {
    f32x2 t = v * 2.88539008f;
    f32x2 e = {fast_exp2(t[0]), fast_exp2(t[1])};
    e = e + 1.0f;
    f32x2 r = {fast_rcp(e[0]), fast_rcp(e[1])};
    return f32x2{1.0f, 1.0f} - 2.0f * r;
}

// float -> bf16 bits (RNE) — setup only
__device__ __forceinline__ unsigned f2bf(float x) {
    unsigned u = __float_as_uint(x);
    unsigned r = u + 0x7FFFu + ((u >> 16) & 1u);
    return r >> 16;
}
__device__ __forceinline__ float bf2f(unsigned b) {
    return __uint_as_float(b << 16);
}

__device__ __forceinline__ unsigned cvt_pk_bf16(float a, float b) {
    unsigned r;
    asm("v_cvt_pk_bf16_f32 %0, %1, %2" : "=v"(r) : "v"(a), "v"(b));
    return r;
}

// Per-step barrier without the vmcnt(0) drain __syncthreads() emits.
// All in-loop cross-wave traffic is LDS (lgkmcnt(0)+s_barrier orders it);
// global ops are write-only stores / same-thread prefetch.
__device__ __forceinline__ void step_barrier() {
    asm volatile("s_waitcnt lgkmcnt(0)\n\ts_barrier" ::: "memory");
}

// ===================== v18: v16 + deferred c-plane pack/writes ==============
// Session finding (R2/R5/R9): step time ~= sum of one wave's issue + trans
// occupancy + LDS latency + barrier — co-resident work adds linearly, never
// overlaps. Only tail-removal wins (R4/R6/R8: 3/3). v18 removes the c-pack
// chain (cvt_pk->bf2f->sub->cvt_pk) and 2 of 3 ds_writes from the barrier
// tail: c0n2 stays in regs; the pack + both c-plane writes run at the TOP of
// the next iteration, inside the ~200cy MFMA-wait window, draining off-chain
// over the whole iteration. Wave 4 lags 2 steps (out[t-2]; its Hbuf[par]
// read index is unchanged by the parity algebra — one barrier always
// separates producer write and consumer read). Also: the 2 chained L1 MFMAs
// become independent accumulators + f32x4 add (one less dependent MFMA
// latency; f32 reassociation only). Zero added ops on the chain.
__global__ __launch_bounds__(320, 1)
void lstm_v18_kernel(const float* __restrict__ input,
                     const float* __restrict__ W_ih0,
                     const float* __restrict__ W_hh0,
                     const float* __restrict__ b_ih0,
                     const float* __restrict__ b_hh0,
                     const float* __restrict__ W_ih1,
                     const float* __restrict__ W_hh1,
                     const float* __restrict__ b_ih1,
                     const float* __restrict__ b_hh1,
                     float* __restrict__ out)
{
    const int tid = threadIdx.x;
    const int w8  = tid >> 6;        // wave 0..3 = L1 compute, wave 4 = L2
    const int l   = tid & 63;
    const int q16 = l >> 4;
    const int n16 = l & 15;
    const int n8  = l & 7;           // batch within block
    const int hi8 = n16 >> 3;
    const int ua  = 16 * w8 + 4 * q16 + 2 * hi8;   // even unit of pair (w8<4)
    const int widx = 8 * w8 + 2 * q16 + hi8;
    const int bbase = blockIdx.x * BTILE;

    __shared__ __align__(16) unsigned Hbuf[2][3][16][HS];   // h, c_hi, c_lo planes
    __shared__ float Xb[2][BTILE][65];                      // 4.2 KB

    for (int i = tid; i < 2 * 3 * 16 * HS; i += 320)
        reinterpret_cast<unsigned*>(Hbuf)[i] = 0u;

    // ---- compute-wave constants ----
    short8 a1[4][2];
    f32x2 wg2[4], bg2[4];
    if (w8 < 4) {
        #pragma unroll
        for (int g = 0; g < 4; ++g) {
            #pragma unroll
            for (int kt = 0; kt < 2; ++kt) {
                const float* p = W_hh0 + (size_t)(16 * (w8 + 4 * g) + n16) * 64 + kt * 32 + q16 * 8;
                short8 a;
                #pragma unroll
                for (int j = 0; j < 8; ++j) a[j] = (short)f2bf(p[j]);
                a1[g][kt] = a;
            }
        }
        #pragma unroll
        for (int g = 0; g < 4; ++g) {
            int rA = g * 64 + ua;
            int rB = rA + 1;
            wg2[g] = f32x2{W_ih0[rA], W_ih0[rB]};
            bg2[g] = f32x2{b_ih0[rA] + b_hh0[rA], b_ih0[rB] + b_hh0[rB]};
        }
    }

    // ---- wave-4 constants: L2 A-fragments (hi/lo split) + recurrence ----
    short8 a2h[2], a2l[2];
    float wh1[4], bb1[4];
    if (w8 == 4) {
        #pragma unroll
        for (int kt = 0; kt < 2; ++kt) {
            short8 ah = {0,0,0,0,0,0,0,0}, al = {0,0,0,0,0,0,0,0};
            if (n16 < 4) {
                const float* p = W_ih1 + (size_t)n16 * 64 + kt * 32 + q16 * 8;
                #pragma unroll
                for (int j = 0; j < 8; ++j) {
                    unsigned hb = f2bf(p[j]);
                    ah[j] = (short)hb;
                    al[j] = (short)f2bf(p[j] - bf2f(hb));
                }
            }
            a2h[kt] = ah; a2l[kt] = al;
        }
        #pragma unroll
        for (int g = 0; g < 4; ++g) { wh1[g] = W_hh1[g]; bb1[g] = b_ih1[g] + b_hh1[g]; }
    }

    // ---- input staging: tid<256, thread (xr, xc) covers rows 0..7 x cols 0..63 ----
    const int xr = (tid >> 5) & 7;
    const int xc = tid & 31;
    const float* rowptr = input + (size_t)(bbase + xr) * T_STEPS;
    if (tid < 256) {
        Xb[0][xr][xc]      = rowptr[xc];
        Xb[0][xr][xc + 32] = rowptr[xc + 32];
    }
    float xnA = 0.0f, xnB = 0.0f;
    f32x2 c02 = {0.0f, 0.0f};
    f32x2 c_sv = {0.0f, 0.0f};       // deferred c0n2 of step t-1 (compute waves)
    float h1 = 0.0f, c1 = 0.0f;      // wave-4 L2 state (lanes 0..7)

    __syncthreads();

    int par = 0;
    #pragma unroll 2
    for (int t = 0; t < T_STEPS; ++t) {
        if (w8 < 4) {
            // ---- deferred: pack + write c(t-1) planes into Hbuf[par^1][1,2].
            //      Runs inside the MFMA/ds_read wait window; drains over the
            //      whole iteration. Wave 4 reads them at iteration t+1. ----
            if (t > 0) {
                unsigned chword = cvt_pk_bf16(c_sv[0], c_sv[1]);
                float hiA = bf2f(chword & 0xFFFFu);
                float hiB = bf2f(chword >> 16);
                f32x2 lo = c_sv - f32x2{hiA, hiB};
                unsigned clword = cvt_pk_bf16(lo[0], lo[1]);
                Hbuf[par ^ 1][1][n8][widx] = chword;
                Hbuf[par ^ 1][2][n8][widx] = clword;
            }

            if ((t & 63) == 0 && t + 64 < T_STEPS) {
                xnA = rowptr[t + 64 + xc];
                xnB = rowptr[t + 64 + xc + 32];
            }
            const int cp = (t >> 6) & 1;

            // ---- B-fragments: h(t-1) ----
            const unsigned* Hrow = &Hbuf[par][0][n16][0];
            short8 hb0 = *reinterpret_cast<const short8*>(Hrow + 4 * q16);
            short8 hb1 = *reinterpret_cast<const short8*>(Hrow + 16 + 4 * q16);

            // ---- L1 MFMA: independent accumulators + add (shorter dep chain) ----
            f32x4 accv[4];
            #pragma unroll
            for (int g = 0; g < 4; ++g) {
                f32x4 zz = {0.0f, 0.0f, 0.0f, 0.0f};
                f32x4 z0 = __builtin_amdgcn_mfma_f32_16x16x32_bf16(a1[g][0], hb0, zz, 0, 0, 0);
                f32x4 z1 = __builtin_amdgcn_mfma_f32_16x16x32_bf16(a1[g][1], hb1, zz, 0, 0, 0);
                accv[g] = z0 + z1;
            }

            // ---- gate select (8 DPP serve the 2 cells) ----
            float vA[4], vB[4];
            #pragma unroll
            for (int g = 0; g < 4; ++g) {
                int pa = __float_as_int(accv[g][0]);
                pa = __builtin_amdgcn_update_dpp(pa, __float_as_int(accv[g][2]), 0x118, 0xf, 0xC, false);
                int pb = __float_as_int(accv[g][1]);
                pb = __builtin_amdgcn_update_dpp(pb, __float_as_int(accv[g][3]), 0x118, 0xf, 0xC, false);
                vA[g] = __int_as_float(pa);
                vB[g] = __int_as_float(pb);
            }

            // ---- layer-1 activation, 2 cells (batch n8, units ua/ua+1) ----
            float x = Xb[cp][n8][t & 63];
            f32x2 xx = {x, x};
            f32x2 gi = f32x2{vA[0], vB[0]} + (xx * wg2[0] + bg2[0]);
            f32x2 gf = f32x2{vA[1], vB[1]} + (xx * wg2[1] + bg2[1]);
            f32x2 gg = f32x2{vA[2], vB[2]} + (xx * wg2[2] + bg2[2]);
            f32x2 go = f32x2{vA[3], vB[3]} + (xx * wg2[3] + bg2[3]);

            f32x2 si = sigf2(gi);
            f32x2 sf = sigf2(gf);
            f32x2 tg = tanh2(gg);
            f32x2 c0n2 = sf * c02 + si * tg;
            c02 = c0n2;
            f32x2 so = sigf2(go);
            f32x2 th = tanh2(c0n2);
            f32x2 h0n2 = so * th;

            // ---- tail: only the h word (loop-carried) hits the barrier drain ----
            Hbuf[par ^ 1][0][n8][widx] = cvt_pk_bf16(h0n2[0], h0n2[1]);
            c_sv = c0n2;                         // c planes deferred to next top

            if ((t & 63) == 63 && t + 1 < T_STEPS) {
                Xb[cp ^ 1][xr][xc]      = xnA;
                Xb[cp ^ 1][xr][xc + 32] = xnB;
            }
        } else {
            // ---- wave 4: L2 GEMV + recurrence for step t-2 (lag 2) ----
            if (t > 1) {
                const unsigned* Ch = &Hbuf[par][1][n16][0];
                const unsigned* Cl = &Hbuf[par][2][n16][0];
                short8 ch0 = *reinterpret_cast<const short8*>(Ch + 4 * q16);
                short8 ch1 = *reinterpret_cast<const short8*>(Ch + 16 + 4 * q16);
                short8 cl0 = *reinterpret_cast<const short8*>(Cl + 4 * q16);
                short8 cl1 = *reinterpret_cast<const short8*>(Cl + 16 + 4 * q16);
                f32x4 zA = {0.0f, 0.0f, 0.0f, 0.0f};
                f32x4 zB = {0.0f, 0.0f, 0.0f, 0.0f};
                zA = __builtin_amdgcn_mfma_f32_16x16x32_bf16(a2h[0], ch0, zA, 0, 0, 0);
                zB = __builtin_amdgcn_mfma_f32_16x16x32_bf16(a2l[1], ch1, zB, 0, 0, 0);
                zA = __builtin_amdgcn_mfma_f32_16x16x32_bf16(a2h[1], ch1, zA, 0, 0, 0);
                zB = __builtin_amdgcn_mfma_f32_16x16x32_bf16(a2h[0], cl0, zB, 0, 0, 0);
                zA = __builtin_amdgcn_mfma_f32_16x16x32_bf16(a2l[0], ch0, zA, 0, 0, 0);
                zB = __builtin_amdgcn_mfma_f32_16x16x32_bf16(a2h[1], cl1, zB, 0, 0, 0);
                f32x4 z = zA + zB;
                if (l < 8) {
                    float gi = z[0] + bb1[0] + h1 * wh1[0];
                    float gf = z[1] + bb1[1] + h1 * wh1[1];
                    float gg = z[2] + bb1[2] + h1 * wh1[2];
                    float go = z[3] + bb1[3] + h1 * wh1[3];
                    float c1n = sigf(gf) * c1 + sigf(gi) * tanh_fast(gg);
                    c1 = c1n;
                    h1 = sigf(go) * tanh_fast(c1n);
                    out[(size_t)(bbase + l) * T_STEPS + (t - 2)] = c1n;
                }
            }
        }

        step_barrier();
        par ^= 1;
    }

    // ---- epilogue 1: compute waves write c(1023) planes (buffer 1) ----
    if (w8 < 4) {
        unsigned chword = cvt_pk_bf16(c_sv[0], c_sv[1]);
        float hiA = bf2f(chword & 0xFFFFu);
        float hiB = bf2f(chword >> 16);
        f32x2 lo = c_sv - f32x2{hiA, hiB};
        unsigned clword = cvt_pk_bf16(lo[0], lo[1]);
        Hbuf[1][1][n8][widx] = chword;
        Hbuf[1][2][n8][widx] = clword;
    }
    step_barrier();

    // ---- epilogue 2: wave 4 flushes steps 1022 (buffer 0) and 1023 (buffer 1) ----
    if (w8 == 4) {
        #pragma unroll
        for (int eb = 0; eb < 2; ++eb) {
            const unsigned* Ch = &Hbuf[eb][1][n16][0];
            const unsigned* Cl = &Hbuf[eb][2][n16][0];
            short8 ch0 = *reinterpret_cast<const short8*>(Ch + 4 * q16);
            short8 ch1 = *reinterpret_cast<const short8*>(Ch + 16 + 4 * q16);
            short8 cl0 = *reinterpret_cast<const short8*>(Cl + 4 * q16);
            short8 cl1 = *reinterpret_cast<const short8*>(Cl + 16 + 4 * q16);
            f32x4 zA = {0.0f, 0.0f, 0.0f, 0.0f};
            f32x4 zB = {0.0f, 0.0f, 0.0f, 0.0f};
            zA = __builtin_amdgcn_mfma_f32_16x16x32_bf16(a2h[0], ch0, zA, 0, 0, 0);
            zB = __builtin_amdgcn_mfma_f32_16x16x32_bf16(a2l[1], ch1, zB, 0, 0, 0);
            zA = __builtin_amdgcn_mfma_f32_16x16x32_bf16(a2h[1], ch1, zA, 0, 0, 0);
            zB = __builtin_amdgcn_mfma_f32_16x16x32_bf16(a2h[0], cl0, zB, 0, 0, 0);
            zA = __builtin_amdgcn_mfma_f32_16x16x32_bf16(a2l[0], ch0, zA, 0, 0, 0);
            zB = __builtin_amdgcn_mfma_f32_16x16x32_bf16(a2h[1], cl1, zB, 0, 0, 0);
            f32x4 z = zA + zB;
            if (l < 8) {
                float gi = z[0] + bb1[0] + h1 * wh1[0];
                float gf = z[1] + bb1[1] + h1 * wh1[1];
                float gg = z[2] + bb1[2] + h1 * wh1[2];
                float go = z[3] + bb1[3] + h1 * wh1[3];
                float c1n = sigf(gf) * c1 + sigf(gi) * tanh_fast(gg);
                c1 = c1n;
                h1 = sigf(go) * tanh_fast(c1n);
                out[(size_t)(bbase + l) * T_STEPS + (T_STEPS - 2 + eb)] = c1n;
            }
        }
    }
}

extern "C" void kernel_launch(void* const* d_in, const int* in_sizes, int n_in,
                              void* d_out, int out_size, void* d_ws, size_t ws_size,
                              hipStream_t stream) {
    const float* input = (const float*)d_in[0];
    const float* W_ih0 = (const float*)d_in[1];
    const float* W_hh0 = (const float*)d_in[2];
    const float* b_ih0 = (const float*)d_in[3];
    const float* b_hh0 = (const float*)d_in[4];
    const float* W_ih1 = (const float*)d_in[5];
    const float* W_hh1 = (const float*)d_in[6];
    const float* b_ih1 = (const float*)d_in[7];
    const float* b_hh1 = (const float*)d_in[8];
    float* out = (float*)d_out;

    lstm_v18_kernel<<<dim3(BATCH / BTILE), dim3(320), 0, stream>>>(
        input, W_ih0, W_hh0, b_ih0, b_hh0, W_ih1, W_hh1, b_ih1, b_hh1, out);
}

// Round 11
// 492.609 us; speedup vs baseline: 1.2536x; 1.0344x over previous
//
#include <hip/hip_runtime.h>

#define T_STEPS 1024
#define BATCH 2048
#define BTILE 8   // 8 batch rows/block -> 256 blocks -> 1 block/CU
#define HS 36     // LDS row stride in u32 words; 36 % 32 == 4 -> conflict-free b128 reads

typedef short short8 __attribute__((ext_vector_type(8)));
typedef float f32x4 __attribute__((ext_vector_type(4)));
typedef float f32x2 __attribute__((ext_vector_type(2)));

__device__ __forceinline__ float fast_rcp(float x) {
#if __has_builtin(__builtin_amdgcn_rcpf)
    return __builtin_amdgcn_rcpf(x);
#else
    return 1.0f / x;
#endif
}

__device__ __forceinline__ float fast_exp2(float x) {
#if __has_builtin(__builtin_amdgcn_exp2f)
    return __builtin_amdgcn_exp2f(x);
#else
    return exp2f(x);
#endif
}

__device__ __forceinline__ float sigf(float x) {
    return fast_rcp(1.0f + fast_exp2(-1.44269504f * x));
}

__device__ __forceinline__ f32x2 sigf2(f32x2 v) {
    f32x2 t = v * (-1.44269504f);
    f32x2 e = {fast_exp2(t[0]), fast_exp2(t[1])};
    e = e + 1.0f;
    return f32x2{fast_rcp(e[0]), fast_rcp(e[1])};
}

__device__ __forceinline__ float tanh_fast(float x) {
    float e = fast_exp2(2.88539008f * x);
    return 1.0f - 2.0f * fast_rcp(e + 1.0f);
}

__device__ __forceinline__ f32x2 tanh2(f32x2 v) {
    f32x2 t = v * 2.88539008f;
    f32x2 e = {fast_exp2(t[0]), fast_exp2(t[1])};
    e = e + 1.0f;
    f32x2 r = {fast_rcp(e[0]), fast_rcp(e[1])};
    return f32x2{1.0f, 1.0f} - 2.0f * r;
}

// float -> bf16 bits (RNE) — setup only
__device__ __forceinline__ unsigned f2bf(float x) {
    unsigned u = __float_as_uint(x);
    unsigned r = u + 0x7FFFu + ((u >> 16) & 1u);
    return r >> 16;
}
__device__ __forceinline__ float bf2f(unsigned b) {
    return __uint_as_float(b << 16);
}

__device__ __forceinline__ unsigned cvt_pk_bf16(float a, float b) {
    unsigned r;
    asm("v_cvt_pk_bf16_f32 %0, %1, %2" : "=v"(r) : "v"(a), "v"(b));
    return r;
}

// Per-step barrier without the vmcnt(0) drain __syncthreads() emits.
// All in-loop cross-wave traffic is LDS (lgkmcnt(0)+s_barrier orders it);
// global ops are write-only stores / same-thread prefetch.
__device__ __forceinline__ void step_barrier() {
    asm volatile("s_waitcnt lgkmcnt(0)\n\ts_barrier" ::: "memory");
}

// ===================== v19: v16 + correctly-placed c-plane defer ============
// v18's defer regressed (478 vs 441 us) because the deferred c ds_writes were
// placed textually BEFORE the critical h ds_read: same-wave LDS ops issue in
// order and the compiler cannot reorder potentially-aliasing LDS accesses, so
// the writes delayed the chain head every step. v19 keeps v16's structure
// (chained MFMA restored) and places the deferred c-pack + 2 ds_writes AFTER
// the MFMA issue (h-reads already queued), inside the ~100+cy MFMA-wait
// window; they drain during activation, fully off the tail. Tail is now just
// h-pack + 1 ds_write. Wave 4 uses v18's verified lag-2 (out[t-2]; the
// Hbuf[par][1,2] read index is unchanged by the parity algebra — c(t-2) was
// written during iteration t-1 into Hbuf[par_t]).
__global__ __launch_bounds__(320, 1)
void lstm_v19_kernel(const float* __restrict__ input,
                     const float* __restrict__ W_ih0,
                     const float* __restrict__ W_hh0,
                     const float* __restrict__ b_ih0,
                     const float* __restrict__ b_hh0,
                     const float* __restrict__ W_ih1,
                     const float* __restrict__ W_hh1,
                     const float* __restrict__ b_ih1,
                     const float* __restrict__ b_hh1,
                     float* __restrict__ out)
{
    const int tid = threadIdx.x;
    const int w8  = tid >> 6;        // wave 0..3 = L1 compute, wave 4 = L2
    const int l   = tid & 63;
    const int q16 = l >> 4;
    const int n16 = l & 15;
    const int n8  = l & 7;           // batch within block
    const int hi8 = n16 >> 3;
    const int ua  = 16 * w8 + 4 * q16 + 2 * hi8;   // even unit of pair (w8<4)
    const int widx = 8 * w8 + 2 * q16 + hi8;
    const int bbase = blockIdx.x * BTILE;

    __shared__ __align__(16) unsigned Hbuf[2][3][16][HS];   // h, c_hi, c_lo planes
    __shared__ float Xb[2][BTILE][65];                      // 4.2 KB

    for (int i = tid; i < 2 * 3 * 16 * HS; i += 320)
        reinterpret_cast<unsigned*>(Hbuf)[i] = 0u;

    // ---- compute-wave constants ----
    short8 a1[4][2];
    f32x2 wg2[4], bg2[4];
    if (w8 < 4) {
        #pragma unroll
        for (int g = 0; g < 4; ++g) {
            #pragma unroll
            for (int kt = 0; kt < 2; ++kt) {
                const float* p = W_hh0 + (size_t)(16 * (w8 + 4 * g) + n16) * 64 + kt * 32 + q16 * 8;
                short8 a;
                #pragma unroll
                for (int j = 0; j < 8; ++j) a[j] = (short)f2bf(p[j]);
                a1[g][kt] = a;
            }
        }
        #pragma unroll
        for (int g = 0; g < 4; ++g) {
            int rA = g * 64 + ua;
            int rB = rA + 1;
            wg2[g] = f32x2{W_ih0[rA], W_ih0[rB]};
            bg2[g] = f32x2{b_ih0[rA] + b_hh0[rA], b_ih0[rB] + b_hh0[rB]};
        }
    }

    // ---- wave-4 constants: L2 A-fragments (hi/lo split) + recurrence ----
    short8 a2h[2], a2l[2];
    float wh1[4], bb1[4];
    if (w8 == 4) {
        #pragma unroll
        for (int kt = 0; kt < 2; ++kt) {
            short8 ah = {0,0,0,0,0,0,0,0}, al = {0,0,0,0,0,0,0,0};
            if (n16 < 4) {
                const float* p = W_ih1 + (size_t)n16 * 64 + kt * 32 + q16 * 8;
                #pragma unroll
                for (int j = 0; j < 8; ++j) {
                    unsigned hb = f2bf(p[j]);
                    ah[j] = (short)hb;
                    al[j] = (short)f2bf(p[j] - bf2f(hb));
                }
            }
            a2h[kt] = ah; a2l[kt] = al;
        }
        #pragma unroll
        for (int g = 0; g < 4; ++g) { wh1[g] = W_hh1[g]; bb1[g] = b_ih1[g] + b_hh1[g]; }
    }

    // ---- input staging: tid<256, thread (xr, xc) covers rows 0..7 x cols 0..63 ----
    const int xr = (tid >> 5) & 7;
    const int xc = tid & 31;
    const float* rowptr = input + (size_t)(bbase + xr) * T_STEPS;
    if (tid < 256) {
        Xb[0][xr][xc]      = rowptr[xc];
        Xb[0][xr][xc + 32] = rowptr[xc + 32];
    }
    float xnA = 0.0f, xnB = 0.0f;
    f32x2 c02 = {0.0f, 0.0f};
    f32x2 c_sv = {0.0f, 0.0f};       // deferred c0n2 of step t-1 (compute waves)
    float h1 = 0.0f, c1 = 0.0f;      // wave-4 L2 state (lanes 0..7)

    __syncthreads();

    int par = 0;
    #pragma unroll 2
    for (int t = 0; t < T_STEPS; ++t) {
        if (w8 < 4) {
            if ((t & 63) == 0 && t + 64 < T_STEPS) {
                xnA = rowptr[t + 64 + xc];
                xnB = rowptr[t + 64 + xc + 32];
            }
            const int cp = (t >> 6) & 1;

            // ---- B-fragments: h(t-1) — chain head, issues FIRST ----
            const unsigned* Hrow = &Hbuf[par][0][n16][0];
            short8 hb0 = *reinterpret_cast<const short8*>(Hrow + 4 * q16);
            short8 hb1 = *reinterpret_cast<const short8*>(Hrow + 16 + 4 * q16);

            // ---- L1 MFMA (chained accumulate, v16-proven) ----
            f32x4 accv[4];
            #pragma unroll
            for (int g = 0; g < 4; ++g) {
                f32x4 z = {0.0f, 0.0f, 0.0f, 0.0f};
                z = __builtin_amdgcn_mfma_f32_16x16x32_bf16(a1[g][0], hb0, z, 0, 0, 0);
                z = __builtin_amdgcn_mfma_f32_16x16x32_bf16(a1[g][1], hb1, z, 0, 0, 0);
                accv[g] = z;
            }

            // ---- deferred c(t-1) pack + writes: AFTER the h-reads/MFMA issue,
            //      inside the MFMA-wait window; drains during activation.
            //      Wave 4 reads these at iteration t+1 (lag 2). ----
            if (t > 0) {
                unsigned chword = cvt_pk_bf16(c_sv[0], c_sv[1]);
                float hiA = bf2f(chword & 0xFFFFu);
                float hiB = bf2f(chword >> 16);
                f32x2 lo = c_sv - f32x2{hiA, hiB};
                unsigned clword = cvt_pk_bf16(lo[0], lo[1]);
                Hbuf[par ^ 1][1][n8][widx] = chword;
                Hbuf[par ^ 1][2][n8][widx] = clword;
            }

            // ---- gate select (8 DPP serve the 2 cells) ----
            float vA[4], vB[4];
            #pragma unroll
            for (int g = 0; g < 4; ++g) {
                int pa = __float_as_int(accv[g][0]);
                pa = __builtin_amdgcn_update_dpp(pa, __float_as_int(accv[g][2]), 0x118, 0xf, 0xC, false);
                int pb = __float_as_int(accv[g][1]);
                pb = __builtin_amdgcn_update_dpp(pb, __float_as_int(accv[g][3]), 0x118, 0xf, 0xC, false);
                vA[g] = __int_as_float(pa);
                vB[g] = __int_as_float(pb);
            }

            // ---- layer-1 activation, 2 cells (batch n8, units ua/ua+1) ----
            float x = Xb[cp][n8][t & 63];
            f32x2 xx = {x, x};
            f32x2 gi = f32x2{vA[0], vB[0]} + (xx * wg2[0] + bg2[0]);
            f32x2 gf = f32x2{vA[1], vB[1]} + (xx * wg2[1] + bg2[1]);
            f32x2 gg = f32x2{vA[2], vB[2]} + (xx * wg2[2] + bg2[2]);
            f32x2 go = f32x2{vA[3], vB[3]} + (xx * wg2[3] + bg2[3]);

            f32x2 si = sigf2(gi);
            f32x2 sf = sigf2(gf);
            f32x2 tg = tanh2(gg);
            f32x2 c0n2 = sf * c02 + si * tg;
            c02 = c0n2;
            f32x2 so = sigf2(go);
            f32x2 th = tanh2(c0n2);
            f32x2 h0n2 = so * th;

            // ---- tail: only the h word (loop-carried) hits the barrier drain ----
            Hbuf[par ^ 1][0][n8][widx] = cvt_pk_bf16(h0n2[0], h0n2[1]);
            c_sv = c0n2;                         // c planes deferred to next iter

            if ((t & 63) == 63 && t + 1 < T_STEPS) {
                Xb[cp ^ 1][xr][xc]      = xnA;
                Xb[cp ^ 1][xr][xc + 32] = xnB;
            }
        } else {
            // ---- wave 4: L2 GEMV + recurrence for step t-2 (lag 2) ----
            if (t > 1) {
                const unsigned* Ch = &Hbuf[par][1][n16][0];
                const unsigned* Cl = &Hbuf[par][2][n16][0];
                short8 ch0 = *reinterpret_cast<const short8*>(Ch + 4 * q16);
                short8 ch1 = *reinterpret_cast<const short8*>(Ch + 16 + 4 * q16);
                short8 cl0 = *reinterpret_cast<const short8*>(Cl + 4 * q16);
                short8 cl1 = *reinterpret_cast<const short8*>(Cl + 16 + 4 * q16);
                f32x4 zA = {0.0f, 0.0f, 0.0f, 0.0f};
                f32x4 zB = {0.0f, 0.0f, 0.0f, 0.0f};
                zA = __builtin_amdgcn_mfma_f32_16x16x32_bf16(a2h[0], ch0, zA, 0, 0, 0);
                zB = __builtin_amdgcn_mfma_f32_16x16x32_bf16(a2l[1], ch1, zB, 0, 0, 0);
                zA = __builtin_amdgcn_mfma_f32_16x16x32_bf16(a2h[1], ch1, zA, 0, 0, 0);
                zB = __builtin_amdgcn_mfma_f32_16x16x32_bf16(a2h[0], cl0, zB, 0, 0, 0);
                zA = __builtin_amdgcn_mfma_f32_16x16x32_bf16(a2l[0], ch0, zA, 0, 0, 0);
                zB = __builtin_amdgcn_mfma_f32_16x16x32_bf16(a2h[1], cl1, zB, 0, 0, 0);
                f32x4 z = zA + zB;
                if (l < 8) {
                    float gi = z[0] + bb1[0] + h1 * wh1[0];
                    float gf = z[1] + bb1[1] + h1 * wh1[1];
                    float gg = z[2] + bb1[2] + h1 * wh1[2];
                    float go = z[3] + bb1[3] + h1 * wh1[3];
                    float c1n = sigf(gf) * c1 + sigf(gi) * tanh_fast(gg);
                    c1 = c1n;
                    h1 = sigf(go) * tanh_fast(c1n);
                    out[(size_t)(bbase + l) * T_STEPS + (t - 2)] = c1n;
                }
            }
        }

        step_barrier();
        par ^= 1;
    }

    // ---- epilogue 1: compute waves write c(1023) planes (buffer 1) ----
    if (w8 < 4) {
        unsigned chword = cvt_pk_bf16(c_sv[0], c_sv[1]);
        float hiA = bf2f(chword & 0xFFFFu);
        float hiB = bf2f(chword >> 16);
        f32x2 lo = c_sv - f32x2{hiA, hiB};
        unsigned clword = cvt_pk_bf16(lo[0], lo[1]);
        Hbuf[1][1][n8][widx] = chword;
        Hbuf[1][2][n8][widx] = clword;
    }
    step_barrier();

    // ---- epilogue 2: wave 4 flushes steps 1022 (buffer 0) and 1023 (buffer 1) ----
    if (w8 == 4) {
        #pragma unroll
        for (int eb = 0; eb < 2; ++eb) {
            const unsigned* Ch = &Hbuf[eb][1][n16][0];
            const unsigned* Cl = &Hbuf[eb][2][n16][0];
            short8 ch0 = *reinterpret_cast<const short8*>(Ch + 4 * q16);
            short8 ch1 = *reinterpret_cast<const short8*>(Ch + 16 + 4 * q16);
            short8 cl0 = *reinterpret_cast<const short8*>(Cl + 4 * q16);
            short8 cl1 = *reinterpret_cast<const short8*>(Cl + 16 + 4 * q16);
            f32x4 zA = {0.0f, 0.0f, 0.0f, 0.0f};
            f32x4 zB = {0.0f, 0.0f, 0.0f, 0.0f};
            zA = __builtin_amdgcn_mfma_f32_16x16x32_bf16(a2h[0], ch0, zA, 0, 0, 0);
            zB = __builtin_amdgcn_mfma_f32_16x16x32_bf16(a2l[1], ch1, zB, 0, 0, 0);
            zA = __builtin_amdgcn_mfma_f32_16x16x32_bf16(a2h[1], ch1, zA, 0, 0, 0);
            zB = __builtin_amdgcn_mfma_f32_16x16x32_bf16(a2h[0], cl0, zB, 0, 0, 0);
            zA = __builtin_amdgcn_mfma_f32_16x16x32_bf16(a2l[0], ch0, zA, 0, 0, 0);
            zB = __builtin_amdgcn_mfma_f32_16x16x32_bf16(a2h[1], cl1, zB, 0, 0, 0);
            f32x4 z = zA + zB;
            if (l < 8) {
                float gi = z[0] + bb1[0] + h1 * wh1[0];
                float gf = z[1] + bb1[1] + h1 * wh1[1];
                float gg = z[2] + bb1[2] + h1 * wh1[2];
                float go = z[3] + bb1[3] + h1 * wh1[3];
                float c1n = sigf(gf) * c1 + sigf(gi) * tanh_fast(gg);
                c1 = c1n;
                h1 = sigf(go) * tanh_fast(c1n);
                out[(size_t)(bbase + l) * T_STEPS + (T_STEPS - 2 + eb)] = c1n;
            }
        }
    }
}

extern "C" void kernel_launch(void* const* d_in, const int* in_sizes, int n_in,
                              void* d_out, int out_size, void* d_ws, size_t ws_size,
                              hipStream_t stream) {
    const float* input = (const float*)d_in[0];
    const float* W_ih0 = (const float*)d_in[1];
    const float* W_hh0 = (const float*)d_in[2];
    const float* b_ih0 = (const float*)d_in[3];
    const float* b_hh0 = (const float*)d_in[4];
    const float* W_ih1 = (const float*)d_in[5];
    const float* W_hh1 = (const float*)d_in[6];
    const float* b_ih1 = (const float*)d_in[7];
    const float* b_hh1 = (const float*)d_in[8];
    float* out = (float*)d_out;

    lstm_v19_kernel<<<dim3(BATCH / BTILE), dim3(320), 0, stream>>>(
        input, W_ih0, W_hh0, b_ih0, b_hh0, W_ih1, W_hh1, b_ih1, b_hh1, out);
}

// Round 12
// 472.742 us; speedup vs baseline: 1.3063x; 1.0420x over previous
//
#include <hip/hip_runtime.h>

#define T_STEPS 1024
#define BATCH 2048
#define BTILE 8   // 8 batch rows/block -> 256 blocks -> 1 block/CU
#define HS 36     // LDS row stride in u32 words; 36 % 32 == 4 -> conflict-free b128 reads

typedef short short8 __attribute__((ext_vector_type(8)));
typedef float f32x4 __attribute__((ext_vector_type(4)));
typedef float f32x2 __attribute__((ext_vector_type(2)));

__device__ __forceinline__ float fast_rcp(float x) {
#if __has_builtin(__builtin_amdgcn_rcpf)
    return __builtin_amdgcn_rcpf(x);
#else
    return 1.0f / x;
#endif
}

__device__ __forceinline__ float fast_exp2(float x) {
#if __has_builtin(__builtin_amdgcn_exp2f)
    return __builtin_amdgcn_exp2f(x);
#else
    return exp2f(x);
#endif
}

__device__ __forceinline__ float sigf(float x) {
    return fast_rcp(1.0f + fast_exp2(-1.44269504f * x));
}

__device__ __forceinline__ f32x2 sigf2(f32x2 v) {
    f32x2 t = v * (-1.44269504f);
    f32x2 e = {fast_exp2(t[0]), fast_exp2(t[1])};
    e = e + 1.0f;
    return f32x2{fast_rcp(e[0]), fast_rcp(e[1])};
}

__device__ __forceinline__ float tanh_fast(float x) {
    float e = fast_exp2(2.88539008f * x);
    return 1.0f - 2.0f * fast_rcp(e + 1.0f);
}

__device__ __forceinline__ f32x2 tanh2(f32x2 v) {
    f32x2 t = v * 2.88539008f;
    f32x2 e = {fast_exp2(t[0]), fast_exp2(t[1])};
    e = e + 1.0f;
    f32x2 r = {fast_rcp(e[0]), fast_rcp(e[1])};
    return f32x2{1.0f, 1.0f} - 2.0f * r;
}

// float -> bf16 bits (RNE) — setup only
__device__ __forceinline__ unsigned f2bf(float x) {
    unsigned u = __float_as_uint(x);
    unsigned r = u + 0x7FFFu + ((u >> 16) & 1u);
    return r >> 16;
}
__device__ __forceinline__ float bf2f(unsigned b) {
    return __uint_as_float(b << 16);
}

__device__ __forceinline__ unsigned cvt_pk_bf16(float a, float b) {
    unsigned r;
    asm("v_cvt_pk_bf16_f32 %0, %1, %2" : "=v"(r) : "v"(a), "v"(b));
    return r;
}

// Per-step barrier without the vmcnt(0) drain __syncthreads() emits.
// All in-loop cross-wave traffic is LDS (lgkmcnt(0)+s_barrier orders it);
// global ops are write-only stores / same-thread prefetch.
__device__ __forceinline__ void step_barrier() {
    asm volatile("s_waitcnt lgkmcnt(0)\n\ts_barrier" ::: "memory");
}

// ===================== v16 (FINAL — session best, 441us dispatch) ===========
// Structure: BTILE=8, 256 blocks (1/CU), 320 threads. Waves 0..3 run the L1
// recurrence (MFMA h-GEMV + 2-cell/thread activation); DEDICATED wave 4 runs
// the L2 GEMV (hi/lo bf16-split MFMA, v12-verified math) + serial recurrence
// + output store, one step behind, off the compute waves' chain.
//
// Session ledger (599us inherited baseline -> 441us):
//  R4: defer L2 recurrence off the barrier chain      (605->520 main)
//  R6: VALU-reduce L2 in-kernel, kill 2nd dispatch    (710->487 total)
//  R8: L2 GEMV on dedicated wave 4, kill swizzle tail (487->441)
// Closed axes (measured, do not revisit):
//  - co-residency/occupancy: adds issue linearly, never hides chain latency
//    (R2 +76%, R5 +30%, R9 +35%)
//  - further tail defers: c-pack/swizzle moves all regress — same-wave LDS
//    ops issue in order, so "deferred" writes still block later chain LDS
//    reads (R7 +31us, R10 +37us, R11 +15us). The c-tail is already hidden
//    under wave-4 slack.
// Remaining step time (~1030cy) is the irreducible serial chain:
// ds_read h -> MFMA -> DPP -> 10-transcendental activation -> h write ->
// lgkm drain + barrier, plus ~170cy issue. Sub-440us needs a different
// algorithm, not a rescheduling of this one.
__global__ __launch_bounds__(320, 1)
void lstm_v16_kernel(const float* __restrict__ input,
                     const float* __restrict__ W_ih0,
                     const float* __restrict__ W_hh0,
                     const float* __restrict__ b_ih0,
                     const float* __restrict__ b_hh0,
                     const float* __restrict__ W_ih1,
                     const float* __restrict__ W_hh1,
                     const float* __restrict__ b_ih1,
                     const float* __restrict__ b_hh1,
                     float* __restrict__ out)
{
    const int tid = threadIdx.x;
    const int w8  = tid >> 6;        // wave 0..3 = L1 compute, wave 4 = L2
    const int l   = tid & 63;
    const int q16 = l >> 4;
    const int n16 = l & 15;
    const int n8  = l & 7;           // batch within block
    const int hi8 = n16 >> 3;
    const int ua  = 16 * w8 + 4 * q16 + 2 * hi8;   // even unit of pair (w8<4)
    const int bbase = blockIdx.x * BTILE;

    __shared__ __align__(16) unsigned Hbuf[2][3][16][HS];   // h, c_hi, c_lo planes
    __shared__ float Xb[2][BTILE][65];                      // 4.2 KB

    for (int i = tid; i < 2 * 3 * 16 * HS; i += 320)
        reinterpret_cast<unsigned*>(Hbuf)[i] = 0u;

    // ---- compute-wave constants ----
    short8 a1[4][2];
    f32x2 wg2[4], bg2[4];
    if (w8 < 4) {
        #pragma unroll
        for (int g = 0; g < 4; ++g) {
            #pragma unroll
            for (int kt = 0; kt < 2; ++kt) {
                const float* p = W_hh0 + (size_t)(16 * (w8 + 4 * g) + n16) * 64 + kt * 32 + q16 * 8;
                short8 a;
                #pragma unroll
                for (int j = 0; j < 8; ++j) a[j] = (short)f2bf(p[j]);
                a1[g][kt] = a;
            }
        }
        #pragma unroll
        for (int g = 0; g < 4; ++g) {
            int rA = g * 64 + ua;
            int rB = rA + 1;
            wg2[g] = f32x2{W_ih0[rA], W_ih0[rB]};
            bg2[g] = f32x2{b_ih0[rA] + b_hh0[rA], b_ih0[rB] + b_hh0[rB]};
        }
    }

    // ---- wave-4 constants: L2 A-fragments (hi/lo split) + recurrence ----
    short8 a2h[2], a2l[2];
    float wh1[4], bb1[4];
    if (w8 == 4) {
        #pragma unroll
        for (int kt = 0; kt < 2; ++kt) {
            short8 ah = {0,0,0,0,0,0,0,0}, al = {0,0,0,0,0,0,0,0};
            if (n16 < 4) {
                const float* p = W_ih1 + (size_t)n16 * 64 + kt * 32 + q16 * 8;
                #pragma unroll
                for (int j = 0; j < 8; ++j) {
                    unsigned hb = f2bf(p[j]);
                    ah[j] = (short)hb;
                    al[j] = (short)f2bf(p[j] - bf2f(hb));
                }
            }
            a2h[kt] = ah; a2l[kt] = al;
        }
        #pragma unroll
        for (int g = 0; g < 4; ++g) { wh1[g] = W_hh1[g]; bb1[g] = b_ih1[g] + b_hh1[g]; }
    }

    // ---- input staging: tid<256, thread (xr, xc) covers rows 0..7 x cols 0..63 ----
    const int xr = (tid >> 5) & 7;
    const int xc = tid & 31;
    const float* rowptr = input + (size_t)(bbase + xr) * T_STEPS;
    if (tid < 256) {
        Xb[0][xr][xc]      = rowptr[xc];
        Xb[0][xr][xc + 32] = rowptr[xc + 32];
    }
    float xnA = 0.0f, xnB = 0.0f;
    f32x2 c02 = {0.0f, 0.0f};
    float h1 = 0.0f, c1 = 0.0f;      // wave-4 L2 state (lanes 0..7)

    __syncthreads();

    int par = 0;
    #pragma unroll 2
    for (int t = 0; t < T_STEPS; ++t) {
        if (w8 < 4) {
            if ((t & 63) == 0 && t + 64 < T_STEPS) {
                xnA = rowptr[t + 64 + xc];
                xnB = rowptr[t + 64 + xc + 32];
            }
            const int cp = (t >> 6) & 1;

            // ---- B-fragments: h(t-1) ----
            const unsigned* Hrow = &Hbuf[par][0][n16][0];
            short8 hb0 = *reinterpret_cast<const short8*>(Hrow + 4 * q16);
            short8 hb1 = *reinterpret_cast<const short8*>(Hrow + 16 + 4 * q16);

            // ---- L1 MFMA ----
            f32x4 accv[4];
            #pragma unroll
            for (int g = 0; g < 4; ++g) {
                f32x4 z = {0.0f, 0.0f, 0.0f, 0.0f};
                z = __builtin_amdgcn_mfma_f32_16x16x32_bf16(a1[g][0], hb0, z, 0, 0, 0);
                z = __builtin_amdgcn_mfma_f32_16x16x32_bf16(a1[g][1], hb1, z, 0, 0, 0);
                accv[g] = z;
            }

            // ---- gate select (8 DPP serve the 2 cells) ----
            float vA[4], vB[4];
            #pragma unroll
            for (int g = 0; g < 4; ++g) {
                int pa = __float_as_int(accv[g][0]);
                pa = __builtin_amdgcn_update_dpp(pa, __float_as_int(accv[g][2]), 0x118, 0xf, 0xC, false);
                int pb = __float_as_int(accv[g][1]);
                pb = __builtin_amdgcn_update_dpp(pb, __float_as_int(accv[g][3]), 0x118, 0xf, 0xC, false);
                vA[g] = __int_as_float(pa);
                vB[g] = __int_as_float(pb);
            }

            // ---- layer-1 activation, 2 cells (batch n8, units ua/ua+1) ----
            float x = Xb[cp][n8][t & 63];
            f32x2 xx = {x, x};
            f32x2 gi = f32x2{vA[0], vB[0]} + (xx * wg2[0] + bg2[0]);
            f32x2 gf = f32x2{vA[1], vB[1]} + (xx * wg2[1] + bg2[1]);
            f32x2 gg = f32x2{vA[2], vB[2]} + (xx * wg2[2] + bg2[2]);
            f32x2 go = f32x2{vA[3], vB[3]} + (xx * wg2[3] + bg2[3]);

            f32x2 si = sigf2(gi);
            f32x2 sf = sigf2(gf);
            f32x2 tg = tanh2(gg);
            f32x2 c0n2 = sf * c02 + si * tg;
            c02 = c0n2;
            f32x2 so = sigf2(go);
            f32x2 th = tanh2(c0n2);
            f32x2 h0n2 = so * th;

            // ---- pack h + c hi/lo (in-thread pairs), 3 ds_writes ----
            const int widx = 8 * w8 + 2 * q16 + hi8;
            unsigned hword  = cvt_pk_bf16(h0n2[0], h0n2[1]);
            Hbuf[par ^ 1][0][n8][widx] = hword;
            unsigned chword = cvt_pk_bf16(c0n2[0], c0n2[1]);
            float hiA = bf2f(chword & 0xFFFFu);
            float hiB = bf2f(chword >> 16);
            f32x2 lo = c0n2 - f32x2{hiA, hiB};
            unsigned clword = cvt_pk_bf16(lo[0], lo[1]);
            Hbuf[par ^ 1][1][n8][widx] = chword;
            Hbuf[par ^ 1][2][n8][widx] = clword;

            if ((t & 63) == 63 && t + 1 < T_STEPS) {
                Xb[cp ^ 1][xr][xc]      = xnA;
                Xb[cp ^ 1][xr][xc + 32] = xnB;
            }
        } else {
            // ---- wave 4: L2 GEMV (6 MFMA, hi/lo) + recurrence for step t-1 ----
            if (t > 0) {
                const unsigned* Ch = &Hbuf[par][1][n16][0];
                const unsigned* Cl = &Hbuf[par][2][n16][0];
                short8 ch0 = *reinterpret_cast<const short8*>(Ch + 4 * q16);
                short8 ch1 = *reinterpret_cast<const short8*>(Ch + 16 + 4 * q16);
                short8 cl0 = *reinterpret_cast<const short8*>(Cl + 4 * q16);
                short8 cl1 = *reinterpret_cast<const short8*>(Cl + 16 + 4 * q16);
                f32x4 zA = {0.0f, 0.0f, 0.0f, 0.0f};
                f32x4 zB = {0.0f, 0.0f, 0.0f, 0.0f};
                zA = __builtin_amdgcn_mfma_f32_16x16x32_bf16(a2h[0], ch0, zA, 0, 0, 0);
                zB = __builtin_amdgcn_mfma_f32_16x16x32_bf16(a2l[1], ch1, zB, 0, 0, 0);
                zA = __builtin_amdgcn_mfma_f32_16x16x32_bf16(a2h[1], ch1, zA, 0, 0, 0);
                zB = __builtin_amdgcn_mfma_f32_16x16x32_bf16(a2h[0], cl0, zB, 0, 0, 0);
                zA = __builtin_amdgcn_mfma_f32_16x16x32_bf16(a2l[0], ch0, zA, 0, 0, 0);
                zB = __builtin_amdgcn_mfma_f32_16x16x32_bf16(a2h[1], cl1, zB, 0, 0, 0);
                f32x4 z = zA + zB;
                if (l < 8) {
                    float gi = z[0] + bb1[0] + h1 * wh1[0];
                    float gf = z[1] + bb1[1] + h1 * wh1[1];
                    float gg = z[2] + bb1[2] + h1 * wh1[2];
                    float go = z[3] + bb1[3] + h1 * wh1[3];
                    float c1n = sigf(gf) * c1 + sigf(gi) * tanh_fast(gg);
                    c1 = c1n;
                    h1 = sigf(go) * tanh_fast(c1n);
                    out[(size_t)(bbase + l) * T_STEPS + (t - 1)] = c1n;
                }
            }
        }

        step_barrier();
        par ^= 1;
    }

    // ---- epilogue: wave 4 processes step 1023 (Hbuf[par] = step-1023 data) ----
    if (w8 == 4) {
        const unsigned* Ch = &Hbuf[par][1][n16][0];
        const unsigned* Cl = &Hbuf[par][2][n16][0];
        short8 ch0 = *reinterpret_cast<const short8*>(Ch + 4 * q16);
        short8 ch1 = *reinterpret_cast<const short8*>(Ch + 16 + 4 * q16);
        short8 cl0 = *reinterpret_cast<const short8*>(Cl + 4 * q16);
        short8 cl1 = *reinterpret_cast<const short8*>(Cl + 16 + 4 * q16);
        f32x4 zA = {0.0f, 0.0f, 0.0f, 0.0f};
        f32x4 zB = {0.0f, 0.0f, 0.0f, 0.0f};
        zA = __builtin_amdgcn_mfma_f32_16x16x32_bf16(a2h[0], ch0, zA, 0, 0, 0);
        zB = __builtin_amdgcn_mfma_f32_16x16x32_bf16(a2l[1], ch1, zB, 0, 0, 0);
        zA = __builtin_amdgcn_mfma_f32_16x16x32_bf16(a2h[1], ch1, zA, 0, 0, 0);
        zB = __builtin_amdgcn_mfma_f32_16x16x32_bf16(a2h[0], cl0, zB, 0, 0, 0);
        zA = __builtin_amdgcn_mfma_f32_16x16x32_bf16(a2l[0], ch0, zA, 0, 0, 0);
        zB = __builtin_amdgcn_mfma_f32_16x16x32_bf16(a2h[1], cl1, zB, 0, 0, 0);
        f32x4 z = zA + zB;
        if (l < 8) {
            float gi = z[0] + bb1[0] + h1 * wh1[0];
            float gf = z[1] + bb1[1] + h1 * wh1[1];
            float gg = z[2] + bb1[2] + h1 * wh1[2];
            float c1n = sigf(gf) * c1 + sigf(gi) * tanh_fast(gg);
            out[(size_t)(bbase + l) * T_STEPS + (T_STEPS - 1)] = c1n;
        }
    }
}

extern "C" void kernel_launch(void* const* d_in, const int* in_sizes, int n_in,
                              void* d_out, int out_size, void* d_ws, size_t ws_size,
                              hipStream_t stream) {
    const float* input = (const float*)d_in[0];
    const float* W_ih0 = (const float*)d_in[1];
    const float* W_hh0 = (const float*)d_in[2];
    const float* b_ih0 = (const float*)d_in[3];
    const float* b_hh0 = (const float*)d_in[4];
    const float* W_ih1 = (const float*)d_in[5];
    const float* W_hh1 = (const float*)d_in[6];
    const float* b_ih1 = (const float*)d_in[7];
    const float* b_hh1 = (const float*)d_in[8];
    float* out = (float*)d_out;

    lstm_v16_kernel<<<dim3(BATCH / BTILE), dim3(320), 0, stream>>>(
        input, W_ih0, W_hh0, b_ih0, b_hh0, W_ih1, W_hh1, b_ih1, b_hh1, out);
}